// Round 8
// baseline (8276.036 us; speedup 1.0000x reference)
//
#include <hip/hip_runtime.h>
#include <hip/hip_bf16.h>

#define S_LEN 4096
#define NTAG 24
#define START_TAG 22
#define STOP_TAG 23
#define SENT 0x7F800001u

// ---------------- ws layout (bytes) ----------------
static const size_t OFF_WT    = 0;                               // [300][2048] f32
static const size_t OFF_XG    = OFF_WT + (size_t)300*2048*4;     // [2][4096][1024] f32 (dead after lstm; walk aliases it)
static const size_t OFF_HS    = OFF_XG + (size_t)2*4096*1024*4;  // [2][4096][256] f32
static const size_t OFF_FEATS = OFF_HS + (size_t)2*4096*256*4;   // [4096][24] f32
static const size_t OFF_BP    = OFF_FEATS + (size_t)4096*24*4;   // [4096][24] u8 backpointers
static const size_t OFF_WALK  = OFF_XG;                          // [32][24][128] u8 (aliases XG)

__device__ __forceinline__ float sigf(float x) {
    return __fdividef(1.f, 1.f + __expf(-x));
}
__device__ __forceinline__ float tanhfast(float x) {
    return 1.f - __fdividef(2.f, 1.f + __expf(2.f * x));
}

// Agent-coherent 16B load (R6-proven): sc1 matches agent-scope atomic cache behavior.
__device__ __forceinline__ float4 load_f4_sc1(const float* p) {
    float4 v;
    asm volatile("global_load_dwordx4 %0, %1, off sc1\n\t"
                 "s_waitcnt vmcnt(0)"
                 : "=v"(v) : "v"(p) : "memory");
    return v;
}

__device__ __forceinline__ float atomic_poll_word(const float* p) {
    float v;
    do {
        v = __hip_atomic_load(p, __ATOMIC_RELAXED, __HIP_MEMORY_SCOPE_AGENT);
    } while (__float_as_uint(v) == SENT);
    return v;
}

// ---------------- prep: transpose W_ih, sentinel-fill HS ----------------
__global__ void prep_kernel(const float* __restrict__ w_ih_f, const float* __restrict__ w_ih_b,
                            float* __restrict__ WT, unsigned int* __restrict__ HSu) {
    int tid = blockIdx.x * blockDim.x + threadIdx.x;
    int nth = gridDim.x * blockDim.x;
    for (int idx = tid; idx < 300 * 2048; idx += nth) {
        int k = idx / 2048, col = idx % 2048;
        WT[idx] = (col < 1024) ? w_ih_f[col * 300 + k] : w_ih_b[(col - 1024) * 300 + k];
    }
    for (int idx = tid; idx < 2 * S_LEN * 256; idx += nth)
        HSu[idx] = SENT;
}

// ---------------- embed + input projection ----------------
__global__ __launch_bounds__(256) void embed_xg_kernel(const int* __restrict__ sentence,
                                                       const float* __restrict__ emb,
                                                       const float* __restrict__ WT,
                                                       const float* __restrict__ b_f,
                                                       const float* __restrict__ b_b,
                                                       float* __restrict__ xg) {
    __shared__ float xs[16][300];
    int s0 = blockIdx.x * 16;
    for (int idx = threadIdx.x; idx < 16 * 300; idx += 256) {
        int si = idx / 300, k = idx - si * 300;
        int wrow = sentence[s0 + si];
        xs[si][k] = emb[(size_t)wrow * 300 + k];
    }
    __syncthreads();
    for (int chunk = 0; chunk < 8; ++chunk) {
        int col = chunk * 256 + threadIdx.x;   // 0..2047
        float acc[16];
#pragma unroll
        for (int s = 0; s < 16; ++s) acc[s] = 0.f;
        for (int k = 0; k < 300; k += 4) {
            float w0 = WT[(k + 0) * 2048 + col];
            float w1 = WT[(k + 1) * 2048 + col];
            float w2 = WT[(k + 2) * 2048 + col];
            float w3 = WT[(k + 3) * 2048 + col];
#pragma unroll
            for (int s = 0; s < 16; ++s) {
                float4 x4 = *reinterpret_cast<const float4*>(&xs[s][k]);
                acc[s] += w0 * x4.x + w1 * x4.y + w2 * x4.z + w3 * x4.w;
            }
        }
        int dir = col >> 10;
        int row = col & 1023;
        float bias = dir ? b_b[row] : b_f[row];
#pragma unroll
        for (int s = 0; s < 16; ++s)
            xg[((size_t)dir * S_LEN + (s0 + s)) * 1024 + row] = acc[s] + bias;
    }
}

// ---------------- recurrent LSTM (EXACT R6 structure — proven 5.59 ms) ----------------
__global__ __launch_bounds__(1024) void lstm_kernel(const float* __restrict__ xg,
                                                    const float* __restrict__ w_hh_f,
                                                    const float* __restrict__ w_hh_b,
                                                    float* __restrict__ hs) {
    const int xslot = blockIdx.x & 7;
    if (xslot > 1) return;                 // 48 inert blocks exit
    const int dir = xslot;
    const int blk = blockIdx.x >> 3;       // 0..7
    const int tid = threadIdx.x;
    const int r4 = tid >> 5;
    const int kc = tid & 31;

    __shared__ float hsk[32 * 10];     // skewed h_prev: word w -> hsk[(w>>3)*10 + (w&7)]
    __shared__ float part[128][33];    // partial sums [gate-row][k-chunk]
    __shared__ float gl[128];          // reduced gates

    const float* whh = dir ? w_hh_b : w_hh_f;   // [1024][256], row = g*256 + h_out
    float w[4][8];
#pragma unroll
    for (int q = 0; q < 4; ++q) {
        int R = r4 * 4 + q;
        int grow = ((R >> 5) << 8) + blk * 32 + (R & 31);
#pragma unroll
        for (int j = 0; j < 8; ++j)
            w[q][j] = whh[(size_t)grow * 256 + kc * 8 + j];
    }

    for (int i = tid; i < 320; i += 1024) hsk[i] = 0.f;   // h(-1) = 0

    const float* xgd = xg + (size_t)dir * S_LEN * 1024;
    float* hsd = hs + (size_t)dir * S_LEN * 256;
    float c = 0.f;
    int growR = 0;
    float xg_cur = 0.f;
    if (tid < 128) {
        growR = ((tid >> 5) << 8) + blk * 32 + (tid & 31);
        xg_cur = xgd[(size_t)(dir ? (S_LEN - 1) : 0) * 1024 + growR];
    }
    __syncthreads();

    for (int step = 0; step < S_LEN; ++step) {
        const int st = dir ? (S_LEN - 1 - step) : step;

        // ---- dot: 4 rows x 8 k per thread (all 16 waves) ----
        float hv[8];
        const int hb = kc * 10;
#pragma unroll
        for (int j = 0; j < 8; ++j) hv[j] = hsk[hb + j];
        float p0 = 0.f, p1 = 0.f, p2 = 0.f, p3 = 0.f;
#pragma unroll
        for (int j = 0; j < 8; ++j) {
            p0 += w[0][j] * hv[j];
            p1 += w[1][j] * hv[j];
            p2 += w[2][j] * hv[j];
            p3 += w[3][j] * hv[j];
        }
        part[r4 * 4 + 0][kc] = p0;
        part[r4 * 4 + 1][kc] = p1;
        part[r4 * 4 + 2][kc] = p2;
        part[r4 * 4 + 3][kc] = p3;
        __syncthreads();                                   // B1

        // ---- reduce 32 partials + xg (waves 0,1) ----
        float xg_nxt = 0.f;
        if (tid < 128) {
            if (step + 1 < S_LEN) {
                const int stn = dir ? (st - 1) : (st + 1);
                xg_nxt = xgd[(size_t)stn * 1024 + growR];  // prefetch, used next iter
            }
            float a0 = 0.f, a1 = 0.f, a2 = 0.f, a3 = 0.f;
#pragma unroll
            for (int k2 = 0; k2 < 32; k2 += 4) {
                a0 += part[tid][k2 + 0];
                a1 += part[tid][k2 + 1];
                a2 += part[tid][k2 + 2];
                a3 += part[tid][k2 + 3];
            }
            gl[tid] = xg_cur + ((a0 + a1) + (a2 + a3));
        }
        __syncthreads();                                   // B2

        // ---- wave 0: gates + own h publish (agent-scope atomic, proven) ----
        if (tid < 32) {
            float gi = gl[tid], gf = gl[32 + tid], gg = gl[64 + tid], go = gl[96 + tid];
            float si = sigf(gi), sf = sigf(gf), so = sigf(go);
            c = sf * c + si * tanhfast(gg);
            float h = so * tanhfast(c);
            __hip_atomic_store(&hsd[(size_t)st * 256 + blk * 32 + tid], h,
                               __ATOMIC_RELAXED, __HIP_MEMORY_SCOPE_AGENT);
            int w0 = blk * 32 + tid;
            hsk[(w0 >> 3) * 10 + (w0 & 7)] = h;            // own slice -> LDS directly
        }
        // ---- wave 2: poll remote 224 words as 56 float4 (sc1 = device coherence point) ----
        else if (tid >= 128 && tid < 192 && step + 1 < S_LEN) {
            const int l = tid - 128;                       // float4 index 0..63
            if ((l >> 3) != blk) {                         // skip own block's 8 float4s
                const float* src = &hsd[(size_t)st * 256 + l * 4];
                float4 v;
                int spins = 0;
                bool ok;
                do {
                    v = load_f4_sc1(src);
                    ok = !(__float_as_uint(v.x) == SENT || __float_as_uint(v.y) == SENT ||
                           __float_as_uint(v.z) == SENT || __float_as_uint(v.w) == SENT);
                } while (!ok && ++spins < 512);
                if (!ok) {                                 // guaranteed-progress fallback
                    v.x = atomic_poll_word(src + 0);
                    v.y = atomic_poll_word(src + 1);
                    v.z = atomic_poll_word(src + 2);
                    v.w = atomic_poll_word(src + 3);
                }
                const int w0 = l * 4;
                const int base = (w0 >> 3) * 10 + (w0 & 7);
                hsk[base + 0] = v.x;
                hsk[base + 1] = v.y;
                hsk[base + 2] = v.z;
                hsk[base + 3] = v.w;
            }
        }
        xg_cur = xg_nxt;
        __syncthreads();                                   // B3
    }
}

// ---------------- feats = h @ w_tag^T + b_tag ----------------
__global__ __launch_bounds__(384) void feats_kernel(const float* __restrict__ hs,
                                                    const float* __restrict__ w_tag,
                                                    const float* __restrict__ b_tag,
                                                    float* __restrict__ feats) {
    __shared__ float ht[16][512];
    int s0 = blockIdx.x * 16;
    for (int idx = threadIdx.x; idx < 16 * 512; idx += 384) {
        int si = idx >> 9, k = idx & 511;
        float v = (k < 256) ? hs[(size_t)(s0 + si) * 256 + k]
                            : hs[(size_t)S_LEN * 256 + (size_t)(s0 + si) * 256 + (k - 256)];
        ht[si][k] = v;
    }
    __syncthreads();
    int si = threadIdx.x / NTAG;
    int t = threadIdx.x - si * NTAG;
    float acc = b_tag[t];
    const float* wr = w_tag + t * 512;
    for (int k = 0; k < 512; k += 4) {
        float4 w4 = *reinterpret_cast<const float4*>(&wr[k]);
        float4 h4 = *reinterpret_cast<const float4*>(&ht[si][k]);
        acc += w4.x * h4.x + w4.y * h4.y + w4.z * h4.z + w4.w * h4.w;
    }
    feats[(size_t)(s0 + si) * NTAG + t] = acc;
}

// ---------------- Viterbi: split-f forward (exact) + chunk-parallel backtrack ----------------
// Forward: wave 0; lanes 0..23 handle from-tags 0..11, lanes 32..55 from-tags 12..23 for to=lane&31.
// max merge tie -> lower f: bit-exact vs sequential jnp.argmax (first max).
// Backtrack: 32 chunks x 24 entry tags walk 128 steps in parallel; 32-deep serial compose.
// Bounded everywhere: no spins, no conditional barriers -> cannot hang.
__global__ __launch_bounds__(1024) void viterbi_kernel(const float* __restrict__ feats,
                                                       const float* __restrict__ trans,
                                                       unsigned char* __restrict__ bp_g,
                                                       unsigned char* __restrict__ walk_g,
                                                       float* __restrict__ out) {
    const int tid = threadIdx.x;
    __shared__ float s_bv;
    __shared__ int s_bti;
    __shared__ unsigned char maps[32][24];
    __shared__ int Bc[32];

    if (tid < 64) {
        const int lane = tid;
        const bool lo = lane < NTAG;
        const bool hi = (lane >= 32) && (lane < 32 + NTAG);
        const bool act = lo || hi;
        const int to = lo ? lane : lane - 32;
        const int fbase = lo ? 0 : 12;
        float wt[12];
#pragma unroll
        for (int j = 0; j < 12; ++j)
            wt[j] = act ? trans[to * NTAG + fbase + j] : -3.0e38f;
        float v = act ? ((to == START_TAG) ? 0.f : -10000.f) : -3.0e38f;
        float feat = act ? feats[to] : 0.f;

        for (int s = 0; s < S_LEN; ++s) {
            float featn = (act && s + 1 < S_LEN) ? feats[(s + 1) * NTAG + to] : 0.f;
            float m1 = -3.0e38f;
            int b1 = fbase;
#pragma unroll
            for (int j = 0; j < 12; ++j) {
                float cand = __shfl(v, fbase + j) + wt[j];   // v for tag f lives in lane f (0..23)
                if (cand > m1) { m1 = cand; b1 = fbase + j; } // first-max within half
            }
            float m2 = __shfl_xor(m1, 32);
            int b2 = __shfl_xor(b1, 32);
            float mlo = lo ? m1 : m2; int blo = lo ? b1 : b2;
            float mhi = lo ? m2 : m1; int bhi = lo ? b2 : b1;
            float m = fmaxf(mlo, mhi);
            int bi = (mhi > mlo) ? bhi : blo;                // tie -> lower f (first max)
            v = m + feat;
            if (lo) bp_g[s * NTAG + lane] = (unsigned char)bi;
            feat = featn;
        }
        // termination: argmax(v + trans[STOP]) with first-max ties
        float wstop = act ? trans[STOP_TAG * NTAG + to] : 0.f;
        float bv = lo ? (v + wstop) : -3.0e38f;
        int bti = lo ? lane : 64;
#pragma unroll
        for (int d = 1; d < 64; d <<= 1) {
            float ov = __shfl_xor(bv, d);
            int oi = __shfl_xor(bti, d);
            if (ov > bv || (ov == bv && oi < bti)) { bv = ov; bti = oi; }
        }
        if (lane == 0) { s_bv = bv; s_bti = bti; }
    }
    __syncthreads();

    // Phase A: per-chunk walks (32 chunks x 24 entry tags; entry = tag at chunk's LAST position)
    if (tid < 32 * NTAG) {
        const int c = tid / NTAG, E = tid - c * NTAG;
        const unsigned char* bpc = bp_g + (size_t)c * 128 * NTAG;
        unsigned char* wk = walk_g + (size_t)(c * NTAG + E) * 128;
        int m = E;
        wk[127] = (unsigned char)m;
        for (int j = 126; j >= 0; --j) {
            m = bpc[(j + 1) * NTAG + m];
            wk[j] = (unsigned char)m;
        }
        maps[c][E] = bpc[m];   // exit tag: bp[c*128][tag@(c*128)] = entry of chunk c-1
    }
    __syncthreads();

    // Phase B: serial compose of 32 chunk boundaries
    if (tid == 0) {
        int t = s_bti;
        for (int c = 31; c >= 0; --c) {
            Bc[c] = t;
            if (c) t = maps[c][t];
        }
        out[0] = s_bv;
    }
    __syncthreads();

    // Phase C: parallel emit
    for (int i = tid; i < S_LEN; i += 1024) {
        int c = i >> 7, j = i & 127;
        out[1 + i] = (float)walk_g[(size_t)(c * NTAG + Bc[c]) * 128 + j];
    }
}

// ---------------- launch ----------------
extern "C" void kernel_launch(void* const* d_in, const int* in_sizes, int n_in,
                              void* d_out, int out_size, void* d_ws, size_t ws_size,
                              hipStream_t stream) {
    const int*   sentence = (const int*)d_in[0];
    const float* emb      = (const float*)d_in[1];
    const float* w_ih_f   = (const float*)d_in[2];
    const float* w_hh_f   = (const float*)d_in[3];
    const float* b_f      = (const float*)d_in[4];
    const float* w_ih_b   = (const float*)d_in[5];
    const float* w_hh_b   = (const float*)d_in[6];
    const float* b_b      = (const float*)d_in[7];
    const float* w_tag    = (const float*)d_in[8];
    const float* b_tag    = (const float*)d_in[9];
    const float* trans    = (const float*)d_in[10];

    char* ws = (char*)d_ws;
    float*         WT    = (float*)(ws + OFF_WT);
    float*         XG    = (float*)(ws + OFF_XG);
    float*         HS    = (float*)(ws + OFF_HS);
    float*         FEATS = (float*)(ws + OFF_FEATS);
    unsigned char* BP    = (unsigned char*)(ws + OFF_BP);
    unsigned char* WALK  = (unsigned char*)(ws + OFF_WALK);   // aliases XG (dead after lstm)

    float* out = (float*)d_out;

    prep_kernel<<<512, 256, 0, stream>>>(w_ih_f, w_ih_b, WT, (unsigned int*)HS);
    embed_xg_kernel<<<S_LEN / 16, 256, 0, stream>>>(sentence, emb, WT, b_f, b_b, XG);
    lstm_kernel<<<64, 1024, 0, stream>>>(XG, w_hh_f, w_hh_b, HS);
    feats_kernel<<<S_LEN / 16, 384, 0, stream>>>(HS, w_tag, b_tag, FEATS);
    viterbi_kernel<<<1, 1024, 0, stream>>>(FEATS, trans, BP, WALK, out);
}